// Round 1
// baseline (600.990 us; speedup 1.0000x reference)
//
#include <hip/hip_runtime.h>

#define NB 8192
#define SS 32
#define HIDDEN 64
#define NEDGE 131072
#define NHEAD 8
#define EMB 64
#define ATT_SCALE 0.35355339059327373f
#define LN_EPS 1e-5f

typedef const float* __restrict__ cfp;

// ---------------- Kernel 1: sparse edge bias -> compact W[NH][S][S] ----------
// W[h][s][t] = sum_{e: src=s, dst=t} (edge_attr[e] . we[:,h] + be[h])
// (graph_id = batch[src] depends only on s, so the dense [B,NH,S,S] bias is
//  W gated by (batch[s]==b) applied in the encoder kernel.)
__global__ __launch_bounds__(256) void edge_bias_kernel(
    cfp edge_attr, const int* __restrict__ edge_index, cfp we, cfp be,
    float* __restrict__ W) {
  __shared__ float ea[64][68];   // 64 edges x EMB, padded stride
  __shared__ float wes[64][8];
  __shared__ float bes[8];
  const int t = threadIdx.x;
  const long ebase = (long)blockIdx.x * 64;
  const float4* src4 = (const float4*)(edge_attr + ebase * EMB);
#pragma unroll
  for (int q = 0; q < 4; ++q) {
    int slot = q * 256 + t;             // 0..1023 float4 slots (coalesced)
    int eL = slot >> 4, c4 = (slot & 15) * 4;
    float4 v = src4[slot];
    *(float4*)&ea[eL][c4] = v;
  }
  if (t < 128) ((float4*)wes)[t] = ((const float4*)we)[t];
  if (t < 8) bes[t] = be[t];
  __syncthreads();

  const int eL = t >> 2;                // 64 edges, 4 threads each
  const int h0 = (t & 3) * 2;          // 2 heads per thread
  float d0 = 0.f, d1 = 0.f;
#pragma unroll
  for (int k = 0; k < 64; ++k) {
    float a = ea[eL][k];
    d0 += a * wes[k][h0];
    d1 += a * wes[k][h0 + 1];
  }
  const long eG = ebase + eL;
  const int s = edge_index[eG];
  const int d = edge_index[NEDGE + eG];
  atomicAdd(&W[(h0 * SS + s) * SS + d], d0 + bes[h0]);
  atomicAdd(&W[((h0 + 1) * SS + s) * SS + d], d1 + bes[h0 + 1]);
}

// ---------------- Kernel 2: fused encoder layer, one block per graph --------
__global__ __launch_bounds__(256) void encoder_kernel(
    cfp x, const int* __restrict__ batch,
    cfp wq, cfp bq, cfp wk, cfp bk, cfp wv, cfp bv, cfp wo, cfp bo,
    cfp ln1g, cfp ln1b, cfp ln2g, cfp ln2b,
    cfp w1, cfp bf1, cfp w2, cfp bf2,
    cfp W, float* __restrict__ out) {
  __shared__ float xs[SS][68];   // x, later x1 = x + attn_out@wo
  __shared__ float yb[SS][68];   // y = LN1(x); later attn head output
  __shared__ float qb[SS][68];   // q; later z = LN2(x1)
  __shared__ float kb[SS][68];   // k; later gelu(z@w1+b1)
  __shared__ float vb[SS][68];   // v
  __shared__ float wbuf[64][64]; // staged weight matrix

  const int t = threadIdx.x;
  const int b = blockIdx.x;
  const int s8 = t >> 3, c8 = (t & 7) * 8;                  // LN mapping
  const int n0 = (t & 15) * 4, s0 = (t >> 4) * 2, s1 = s0 + 1;  // MM mapping

  // ---- load x tile + LN1 (register-resident per 8-lane row group) ----
  {
    float xv[8];
    const float4* px = (const float4*)(x + ((long)b * SS + s8) * HIDDEN + c8);
    float4 a = px[0], c = px[1];
    xv[0]=a.x; xv[1]=a.y; xv[2]=a.z; xv[3]=a.w;
    xv[4]=c.x; xv[5]=c.y; xv[6]=c.z; xv[7]=c.w;
    *(float4*)&xs[s8][c8] = a;
    *(float4*)&xs[s8][c8 + 4] = c;
    float sum = 0.f;
#pragma unroll
    for (int i = 0; i < 8; ++i) sum += xv[i];
    sum += __shfl_xor(sum, 1); sum += __shfl_xor(sum, 2); sum += __shfl_xor(sum, 4);
    const float m = sum * (1.f / 64.f);
    float sq = 0.f;
#pragma unroll
    for (int i = 0; i < 8; ++i) { float dd = xv[i] - m; sq += dd * dd; }
    sq += __shfl_xor(sq, 1); sq += __shfl_xor(sq, 2); sq += __shfl_xor(sq, 4);
    const float rs = rsqrtf(sq * (1.f / 64.f) + LN_EPS);
    float gv[8], bv2[8];
    *(float4*)&gv[0]  = *(const float4*)(ln1g + c8);
    *(float4*)&gv[4]  = *(const float4*)(ln1g + c8 + 4);
    *(float4*)&bv2[0] = *(const float4*)(ln1b + c8);
    *(float4*)&bv2[4] = *(const float4*)(ln1b + c8 + 4);
#pragma unroll
    for (int i = 0; i < 8; ++i)
      yb[s8][c8 + i] = (xv[i] - m) * rs * gv[i] + bv2[i];
  }

  float a0[4], a1[4];
  auto load_w = [&](cfp wsrc) {
#pragma unroll
    for (int q = 0; q < 4; ++q) {
      int idx = q * 256 + t;
      ((float4*)&wbuf[0][0])[idx] = ((const float4*)wsrc)[idx];
    }
  };
  auto mm = [&](const float (*SRC)[68]) {
#pragma unroll
    for (int j = 0; j < 4; ++j) { a0[j] = 0.f; a1[j] = 0.f; }
#pragma unroll
    for (int k4 = 0; k4 < 16; ++k4) {
      float4 sa = *(const float4*)&SRC[s0][k4 * 4];
      float4 sb = *(const float4*)&SRC[s1][k4 * 4];
#pragma unroll
      for (int j = 0; j < 4; ++j) {
        float4 w4 = *(const float4*)&wbuf[k4 * 4 + j][n0];
        float av = ((const float*)&sa)[j], bvv = ((const float*)&sb)[j];
        a0[0] += av * w4.x; a0[1] += av * w4.y; a0[2] += av * w4.z; a0[3] += av * w4.w;
        a1[0] += bvv * w4.x; a1[1] += bvv * w4.y; a1[2] += bvv * w4.z; a1[3] += bvv * w4.w;
      }
    }
  };

  // ---- QKV projections ----
  __syncthreads();
  load_w(wq); __syncthreads();
  mm(yb);
  {
    float bb[4]; *(float4*)bb = *(const float4*)(bq + n0);
#pragma unroll
    for (int j = 0; j < 4; ++j) { qb[s0][n0+j] = a0[j] + bb[j]; qb[s1][n0+j] = a1[j] + bb[j]; }
  }
  __syncthreads();
  load_w(wk); __syncthreads();
  mm(yb);
  {
    float bb[4]; *(float4*)bb = *(const float4*)(bk + n0);
#pragma unroll
    for (int j = 0; j < 4; ++j) { kb[s0][n0+j] = a0[j] + bb[j]; kb[s1][n0+j] = a1[j] + bb[j]; }
  }
  __syncthreads();
  load_w(wv); __syncthreads();
  mm(yb);
  {
    float bb[4]; *(float4*)bb = *(const float4*)(bv + n0);
#pragma unroll
    for (int j = 0; j < 4; ++j) { vb[s0][n0+j] = a0[j] + bb[j]; vb[s1][n0+j] = a1[j] + bb[j]; }
  }
  __syncthreads();

  // ---- attention: thread = (head, row); scores fully in registers ----
  {
    const int h = t >> 5, sA = t & 31;
    float q8[8];
    *(float4*)&q8[0] = *(const float4*)&qb[sA][h * 8];
    *(float4*)&q8[4] = *(const float4*)&qb[sA][h * 8 + 4];
    float sc[32];
#pragma unroll
    for (int t2 = 0; t2 < 32; ++t2) {
      float4 ka = *(const float4*)&kb[t2][h * 8];
      float4 kc = *(const float4*)&kb[t2][h * 8 + 4];
      sc[t2] = (q8[0]*ka.x + q8[1]*ka.y + q8[2]*ka.z + q8[3]*ka.w +
                q8[4]*kc.x + q8[5]*kc.y + q8[6]*kc.z + q8[7]*kc.w) * ATT_SCALE;
    }
    if (batch[sA] == b) {
      cfp wr = W + (h * SS + sA) * SS;
#pragma unroll
      for (int t2 = 0; t2 < 32; ++t2) sc[t2] += wr[t2];
    }
    float mx = sc[0];
#pragma unroll
    for (int t2 = 1; t2 < 32; ++t2) mx = fmaxf(mx, sc[t2]);
    float ssum = 0.f;
#pragma unroll
    for (int t2 = 0; t2 < 32; ++t2) { sc[t2] = __expf(sc[t2] - mx); ssum += sc[t2]; }
    const float inv = 1.f / ssum;
    float o[8] = {0,0,0,0,0,0,0,0};
#pragma unroll
    for (int t2 = 0; t2 < 32; ++t2) {
      float p = sc[t2] * inv;
      float4 va = *(const float4*)&vb[t2][h * 8];
      float4 vc = *(const float4*)&vb[t2][h * 8 + 4];
      o[0]+=p*va.x; o[1]+=p*va.y; o[2]+=p*va.z; o[3]+=p*va.w;
      o[4]+=p*vc.x; o[5]+=p*vc.y; o[6]+=p*vc.z; o[7]+=p*vc.w;
    }
    *(float4*)&yb[sA][h * 8]     = make_float4(o[0],o[1],o[2],o[3]);
    *(float4*)&yb[sA][h * 8 + 4] = make_float4(o[4],o[5],o[6],o[7]);
  }
  __syncthreads();

  // ---- output projection + residual -> x1 (in xs) ----
  load_w(wo); __syncthreads();
  mm(yb);
  {
    float bb[4]; *(float4*)bb = *(const float4*)(bo + n0);
#pragma unroll
    for (int j = 0; j < 4; ++j) {
      xs[s0][n0+j] = a0[j] + bb[j] + xs[s0][n0+j];
      xs[s1][n0+j] = a1[j] + bb[j] + xs[s1][n0+j];
    }
  }
  __syncthreads();

  // ---- LN2 -> z (in qb) ----
  {
    float zv[8];
    *(float4*)&zv[0] = *(const float4*)&xs[s8][c8];
    *(float4*)&zv[4] = *(const float4*)&xs[s8][c8 + 4];
    float sum = 0.f;
#pragma unroll
    for (int i = 0; i < 8; ++i) sum += zv[i];
    sum += __shfl_xor(sum, 1); sum += __shfl_xor(sum, 2); sum += __shfl_xor(sum, 4);
    const float m = sum * (1.f / 64.f);
    float sq = 0.f;
#pragma unroll
    for (int i = 0; i < 8; ++i) { float dd = zv[i] - m; sq += dd * dd; }
    sq += __shfl_xor(sq, 1); sq += __shfl_xor(sq, 2); sq += __shfl_xor(sq, 4);
    const float rs = rsqrtf(sq * (1.f / 64.f) + LN_EPS);
    float gv[8], bv2[8];
    *(float4*)&gv[0]  = *(const float4*)(ln2g + c8);
    *(float4*)&gv[4]  = *(const float4*)(ln2g + c8 + 4);
    *(float4*)&bv2[0] = *(const float4*)(ln2b + c8);
    *(float4*)&bv2[4] = *(const float4*)(ln2b + c8 + 4);
#pragma unroll
    for (int i = 0; i < 8; ++i)
      qb[s8][c8 + i] = (zv[i] - m) * rs * gv[i] + bv2[i];
  }
  __syncthreads();

  // ---- FFN1 + exact GELU -> kb ----
  load_w(w1); __syncthreads();
  mm(qb);
  {
    float bb[4]; *(float4*)bb = *(const float4*)(bf1 + n0);
#pragma unroll
    for (int j = 0; j < 4; ++j) {
      float u0 = a0[j] + bb[j];
      float u1 = a1[j] + bb[j];
      kb[s0][n0+j] = 0.5f * u0 * (1.f + erff(u0 * 0.70710678118654752f));
      kb[s1][n0+j] = 0.5f * u1 * (1.f + erff(u1 * 0.70710678118654752f));
    }
  }
  __syncthreads();

  // ---- FFN2 + residual -> global out ----
  load_w(w2); __syncthreads();
  mm(kb);
  {
    float bb[4]; *(float4*)bb = *(const float4*)(bf2 + n0);
    float4 r0, r1;
    r0.x = a0[0] + bb[0] + xs[s0][n0+0];
    r0.y = a0[1] + bb[1] + xs[s0][n0+1];
    r0.z = a0[2] + bb[2] + xs[s0][n0+2];
    r0.w = a0[3] + bb[3] + xs[s0][n0+3];
    r1.x = a1[0] + bb[0] + xs[s1][n0+0];
    r1.y = a1[1] + bb[1] + xs[s1][n0+1];
    r1.z = a1[2] + bb[2] + xs[s1][n0+2];
    r1.w = a1[3] + bb[3] + xs[s1][n0+3];
    *(float4*)(out + ((long)b * SS + s0) * HIDDEN + n0) = r0;
    *(float4*)(out + ((long)b * SS + s1) * HIDDEN + n0) = r1;
  }
}

extern "C" void kernel_launch(void* const* d_in, const int* in_sizes, int n_in,
                              void* d_out, int out_size, void* d_ws, size_t ws_size,
                              hipStream_t stream) {
  (void)in_sizes; (void)n_in; (void)out_size; (void)ws_size;
  cfp x         = (cfp)d_in[0];
  cfp edge_attr = (cfp)d_in[1];
  const int* edge_index = (const int*)d_in[2];
  const int* batch      = (const int*)d_in[3];
  cfp wq = (cfp)d_in[4];  cfp bq = (cfp)d_in[5];
  cfp wk = (cfp)d_in[6];  cfp bk = (cfp)d_in[7];
  cfp wv = (cfp)d_in[8];  cfp bv = (cfp)d_in[9];
  cfp we = (cfp)d_in[10]; cfp be = (cfp)d_in[11];
  cfp wo = (cfp)d_in[12]; cfp bo = (cfp)d_in[13];
  cfp ln1g = (cfp)d_in[14]; cfp ln1b = (cfp)d_in[15];
  cfp ln2g = (cfp)d_in[16]; cfp ln2b = (cfp)d_in[17];
  cfp w1 = (cfp)d_in[18]; cfp bf1 = (cfp)d_in[19];
  cfp w2 = (cfp)d_in[20]; cfp bf2 = (cfp)d_in[21];
  float* out = (float*)d_out;
  float* W = (float*)d_ws;   // NH*S*S floats = 32 KB

  hipMemsetAsync(d_ws, 0, NHEAD * SS * SS * sizeof(float), stream);
  edge_bias_kernel<<<NEDGE / 64, 256, 0, stream>>>(edge_attr, edge_index, we, be, W);
  encoder_kernel<<<NB, 256, 0, stream>>>(x, batch,
      wq, bq, wk, bk, wv, bv, wo, bo,
      ln1g, ln1b, ln2g, ln2b, w1, bf1, w2, bf2, W, out);
}

// Round 2
// 189.306 us; speedup vs baseline: 3.1747x; 3.1747x over previous
//
#include <hip/hip_runtime.h>

#define NB 8192
#define SS 32
#define HIDDEN 64
#define NEDGE 131072
#define NHEAD 8
#define EMB 64
#define GPB 8                      // graphs per block
#define ATT_SCALE 0.35355339059327373f
#define LN_EPS 1e-5f

typedef const float* __restrict__ cfp;
typedef __attribute__((ext_vector_type(8))) short bfrag;   // 8 bf16 (4 VGPRs)
typedef __attribute__((ext_vector_type(4))) float f32x4;

__device__ inline short f2bf(float f) {                    // RNE f32 -> bf16
  union { float f; unsigned u; } un; un.f = f;
  unsigned r = un.u + 0x7FFFu + ((un.u >> 16) & 1u);
  return (short)(r >> 16);
}
__device__ inline float bf2f(short s) {
  union { unsigned u; float f; } un;
  un.u = ((unsigned)(unsigned short)s) << 16;
  return un.f;
}

// ---------------- Kernel 1: sparse edge bias -> compact W[NH][S][S] ----------
__global__ __launch_bounds__(256) void edge_bias_kernel(
    cfp edge_attr, const int* __restrict__ edge_index, cfp we, cfp be,
    float* __restrict__ W) {
  __shared__ float ea[64][68];
  __shared__ float wes[64][8];
  __shared__ float bes[8];
  const int t = threadIdx.x;
  const long ebase = (long)blockIdx.x * 64;
  const float4* src4 = (const float4*)(edge_attr + ebase * EMB);
#pragma unroll
  for (int q = 0; q < 4; ++q) {
    int slot = q * 256 + t;
    int eL = slot >> 4, c4 = (slot & 15) * 4;
    float4 v = src4[slot];
    *(float4*)&ea[eL][c4] = v;
  }
  if (t < 128) ((float4*)wes)[t] = ((const float4*)we)[t];
  if (t < 8) bes[t] = be[t];
  __syncthreads();

  const int eL = t >> 2;
  const int h0 = (t & 3) * 2;
  float d0 = 0.f, d1 = 0.f;
#pragma unroll
  for (int k = 0; k < 64; ++k) {
    float a = ea[eL][k];
    d0 += a * wes[k][h0];
    d1 += a * wes[k][h0 + 1];
  }
  const long eG = ebase + eL;
  const int s = edge_index[eG];
  const int d = edge_index[NEDGE + eG];
  atomicAdd(&W[(h0 * SS + s) * SS + d], d0 + bes[h0]);
  atomicAdd(&W[((h0 + 1) * SS + s) * SS + d], d1 + bes[h0 + 1]);
}

// ---------------- Kernel 2: fused encoder, 8 graphs per block, MFMA GEMMs ---
__global__ __launch_bounds__(256, 2) void encoder_kernel(
    cfp x, const int* __restrict__ batch,
    cfp wq, cfp bq, cfp wk, cfp bk, cfp wv, cfp bv, cfp wo, cfp bo,
    cfp ln1g, cfp ln1b, cfp ln2g, cfp ln2b,
    cfp w1, cfp bf1, cfp w2, cfp bf2,
    cfp W, float* __restrict__ out) {

  // weights transposed: wt[m][n*72 + k] = bf16(w[k][n]); pad 72 for banks
  __shared__ short wt[6][64 * 72];
  __shared__ short ybuf[32 * 72], qbuf[32 * 72], kbuf[32 * 72],
                   vbuf[32 * 72], xbuf[32 * 72];
  __shared__ float bias_s[10][64];  // bq bk bv bo b1 b2 ln1g ln1b ln2g ln2b
  __shared__ int batch_s[SS];

  const int t = threadIdx.x;

  // ---- one-time staging ----
  {
    const int n = t & 63, half = t >> 6;   // each thread: 16 k's of column n
    auto stage_w = [&](cfp src, short* dst) {
      bfrag p0, p1;
#pragma unroll
      for (int j = 0; j < 8; ++j) {
        p0[j] = f2bf(src[(half * 16 + j) * 64 + n]);
        p1[j] = f2bf(src[(half * 16 + 8 + j) * 64 + n]);
      }
      *(bfrag*)&dst[n * 72 + half * 16] = p0;
      *(bfrag*)&dst[n * 72 + half * 16 + 8] = p1;
    };
    stage_w(wq, wt[0]); stage_w(wk, wt[1]); stage_w(wv, wt[2]);
    stage_w(wo, wt[3]); stage_w(w1, wt[4]); stage_w(w2, wt[5]);
  }
  if (t < 64) {
    bias_s[0][t] = bq[t];   bias_s[1][t] = bk[t];   bias_s[2][t] = bv[t];
    bias_s[3][t] = bo[t];   bias_s[4][t] = bf1[t];  bias_s[5][t] = bf2[t];
    bias_s[6][t] = ln1g[t]; bias_s[7][t] = ln1b[t];
    bias_s[8][t] = ln2g[t]; bias_s[9][t] = ln2b[t];
  }
  if (t < SS) batch_s[t] = batch[t];
  __syncthreads();

  const int lane = t & 63, w = t >> 6;
  const int g = lane >> 4, r = lane & 15;      // MFMA fragment coords
  const int tr = w >> 1, tc0 = (w & 1) * 2;    // wave -> 2 output tiles
  const int s8 = t >> 3, c8 = (t & 7) * 8;     // LN mapping
  const int hA = t >> 5, sA = t & 31;          // attention mapping

  // A-fragment loader (row-major bf16 buf, stride 72) and 2-tile GEMM
  auto gemm2 = [&](const short* A, const short* Wt, f32x4 acc[2]) {
    bfrag a0 = *(const bfrag*)&A[(tr * 16 + r) * 72 + g * 8];
    bfrag a1 = *(const bfrag*)&A[(tr * 16 + r) * 72 + 32 + g * 8];
#pragma unroll
    for (int i = 0; i < 2; ++i) {
      const int tc = tc0 + i;
      bfrag b0 = *(const bfrag*)&Wt[(tc * 16 + r) * 72 + g * 8];
      bfrag b1 = *(const bfrag*)&Wt[(tc * 16 + r) * 72 + 32 + g * 8];
      acc[i] = __builtin_amdgcn_mfma_f32_16x16x32_bf16(a0, b0, acc[i], 0, 0, 0);
      acc[i] = __builtin_amdgcn_mfma_f32_16x16x32_bf16(a1, b1, acc[i], 0, 0, 0);
    }
  };
  const f32x4 zero4 = {0.f, 0.f, 0.f, 0.f};

  for (int gi = 0; gi < GPB; ++gi) {
    const long gidx = (long)blockIdx.x * GPB + gi;
    cfp xg = x + gidx * (SS * HIDDEN);

    // ---- phase 1: LN1 -> ybuf (bf16) ----
    {
      float xv[8];
      const float4* px = (const float4*)(xg + s8 * HIDDEN + c8);
      float4 a = px[0], c = px[1];
      xv[0]=a.x; xv[1]=a.y; xv[2]=a.z; xv[3]=a.w;
      xv[4]=c.x; xv[5]=c.y; xv[6]=c.z; xv[7]=c.w;
      float sum = 0.f;
#pragma unroll
      for (int i = 0; i < 8; ++i) sum += xv[i];
      sum += __shfl_xor(sum, 1); sum += __shfl_xor(sum, 2); sum += __shfl_xor(sum, 4);
      const float m = sum * (1.f / 64.f);
      float sq = 0.f;
#pragma unroll
      for (int i = 0; i < 8; ++i) { float dd = xv[i] - m; sq += dd * dd; }
      sq += __shfl_xor(sq, 1); sq += __shfl_xor(sq, 2); sq += __shfl_xor(sq, 4);
      const float rs = rsqrtf(sq * (1.f / 64.f) + LN_EPS);
      bfrag yv;
#pragma unroll
      for (int i = 0; i < 8; ++i)
        yv[i] = f2bf((xv[i] - m) * rs * bias_s[6][c8 + i] + bias_s[7][c8 + i]);
      *(bfrag*)&ybuf[s8 * 72 + c8] = yv;
    }
    __syncthreads();

    // ---- phase 2: QKV projections (MFMA) ----
    {
      bfrag a0 = *(const bfrag*)&ybuf[(tr * 16 + r) * 72 + g * 8];
      bfrag a1 = *(const bfrag*)&ybuf[(tr * 16 + r) * 72 + 32 + g * 8];
      f32x4 acc[3][2];
#pragma unroll
      for (int m = 0; m < 3; ++m) { acc[m][0] = zero4; acc[m][1] = zero4; }
#pragma unroll
      for (int i = 0; i < 2; ++i) {
        const int tc = tc0 + i;
#pragma unroll
        for (int m = 0; m < 3; ++m) {
          bfrag b0 = *(const bfrag*)&wt[m][(tc * 16 + r) * 72 + g * 8];
          bfrag b1 = *(const bfrag*)&wt[m][(tc * 16 + r) * 72 + 32 + g * 8];
          acc[m][i] = __builtin_amdgcn_mfma_f32_16x16x32_bf16(a0, b0, acc[m][i], 0, 0, 0);
          acc[m][i] = __builtin_amdgcn_mfma_f32_16x16x32_bf16(a1, b1, acc[m][i], 0, 0, 0);
        }
      }
      auto epi = [&](const f32x4* am, const float* brow, short* dst) {
#pragma unroll
        for (int i = 0; i < 2; ++i) {
          const int col = (tc0 + i) * 16 + r;
          const float bb = brow[col];
#pragma unroll
          for (int j = 0; j < 4; ++j)
            dst[(tr * 16 + g * 4 + j) * 72 + col] = f2bf(am[i][j] + bb);
        }
      };
      epi(acc[0], bias_s[0], qbuf);
      epi(acc[1], bias_s[1], kbuf);
      epi(acc[2], bias_s[2], vbuf);
    }
    __syncthreads();

    // ---- phase 3: attention (VALU, scores in registers) ----
    {
      bfrag q8 = *(const bfrag*)&qbuf[sA * 72 + hA * 8];
      float qf[8];
#pragma unroll
      for (int j = 0; j < 8; ++j) qf[j] = bf2f(q8[j]);
      float sc[32];
#pragma unroll
      for (int t2 = 0; t2 < 32; ++t2) {
        bfrag k8 = *(const bfrag*)&kbuf[t2 * 72 + hA * 8];
        float d = 0.f;
#pragma unroll
        for (int j = 0; j < 8; ++j) d += qf[j] * bf2f(k8[j]);
        sc[t2] = d * ATT_SCALE;
      }
      if (batch_s[sA] == (int)gidx) {
        cfp wr = W + (hA * SS + sA) * SS;
#pragma unroll
        for (int t2 = 0; t2 < 32; ++t2) sc[t2] += wr[t2];
      }
      float mx = sc[0];
#pragma unroll
      for (int t2 = 1; t2 < 32; ++t2) mx = fmaxf(mx, sc[t2]);
      float ssum = 0.f;
#pragma unroll
      for (int t2 = 0; t2 < 32; ++t2) { sc[t2] = __expf(sc[t2] - mx); ssum += sc[t2]; }
      const float inv = 1.f / ssum;
      float o[8] = {0.f,0.f,0.f,0.f,0.f,0.f,0.f,0.f};
#pragma unroll
      for (int t2 = 0; t2 < 32; ++t2) {
        float p = sc[t2] * inv;
        bfrag v8 = *(const bfrag*)&vbuf[t2 * 72 + hA * 8];
#pragma unroll
        for (int j = 0; j < 8; ++j) o[j] += p * bf2f(v8[j]);
      }
      bfrag ov;
#pragma unroll
      for (int j = 0; j < 8; ++j) ov[j] = f2bf(o[j]);
      *(bfrag*)&ybuf[sA * 72 + hA * 8] = ov;
    }
    __syncthreads();

    // ---- phase 4: out-proj + residual; x1 -> regs (f32) + xbuf (bf16) ----
    float rx1[2][4];
    {
      f32x4 acc[2] = {zero4, zero4};
      gemm2(ybuf, wt[3], acc);
#pragma unroll
      for (int i = 0; i < 2; ++i) {
        const int col = (tc0 + i) * 16 + r;
        const float bb = bias_s[3][col];
#pragma unroll
        for (int j = 0; j < 4; ++j) {
          const int row = tr * 16 + g * 4 + j;
          float v = acc[i][j] + bb + xg[row * HIDDEN + col];
          rx1[i][j] = v;
          xbuf[row * 72 + col] = f2bf(v);
        }
      }
    }
    __syncthreads();

    // ---- phase 5: LN2 -> ybuf (bf16) ----
    {
      bfrag xv8 = *(const bfrag*)&xbuf[s8 * 72 + c8];
      float zv[8];
#pragma unroll
      for (int i = 0; i < 8; ++i) zv[i] = bf2f(xv8[i]);
      float sum = 0.f;
#pragma unroll
      for (int i = 0; i < 8; ++i) sum += zv[i];
      sum += __shfl_xor(sum, 1); sum += __shfl_xor(sum, 2); sum += __shfl_xor(sum, 4);
      const float m = sum * (1.f / 64.f);
      float sq = 0.f;
#pragma unroll
      for (int i = 0; i < 8; ++i) { float dd = zv[i] - m; sq += dd * dd; }
      sq += __shfl_xor(sq, 1); sq += __shfl_xor(sq, 2); sq += __shfl_xor(sq, 4);
      const float rs = rsqrtf(sq * (1.f / 64.f) + LN_EPS);
      bfrag zb;
#pragma unroll
      for (int i = 0; i < 8; ++i)
        zb[i] = f2bf((zv[i] - m) * rs * bias_s[8][c8 + i] + bias_s[9][c8 + i]);
      *(bfrag*)&ybuf[s8 * 72 + c8] = zb;
    }
    __syncthreads();

    // ---- phase 6: FFN1 + exact GELU -> kbuf ----
    {
      f32x4 acc[2] = {zero4, zero4};
      gemm2(ybuf, wt[4], acc);
#pragma unroll
      for (int i = 0; i < 2; ++i) {
        const int col = (tc0 + i) * 16 + r;
        const float bb = bias_s[4][col];
#pragma unroll
        for (int j = 0; j < 4; ++j) {
          const int row = tr * 16 + g * 4 + j;
          float u = acc[i][j] + bb;
          float ge = 0.5f * u * (1.f + erff(u * 0.70710678118654752f));
          kbuf[row * 72 + col] = f2bf(ge);
        }
      }
    }
    __syncthreads();

    // ---- phase 7: FFN2 + residual -> global out ----
    {
      f32x4 acc[2] = {zero4, zero4};
      gemm2(kbuf, wt[5], acc);
      float* og = out + gidx * (SS * HIDDEN);
#pragma unroll
      for (int i = 0; i < 2; ++i) {
        const int col = (tc0 + i) * 16 + r;
        const float bb = bias_s[5][col];
#pragma unroll
        for (int j = 0; j < 4; ++j) {
          const int row = tr * 16 + g * 4 + j;
          og[row * HIDDEN + col] = acc[i][j] + bb + rx1[i][j];
        }
      }
    }
    // no barrier needed: next phase 1 only writes ybuf/xbuf (readers already
    // past barriers), and phase-2 kbuf writes are fenced by phase-1's barrier.
  }
}

extern "C" void kernel_launch(void* const* d_in, const int* in_sizes, int n_in,
                              void* d_out, int out_size, void* d_ws, size_t ws_size,
                              hipStream_t stream) {
  (void)in_sizes; (void)n_in; (void)out_size; (void)ws_size;
  cfp x         = (cfp)d_in[0];
  cfp edge_attr = (cfp)d_in[1];
  const int* edge_index = (const int*)d_in[2];
  const int* batch      = (const int*)d_in[3];
  cfp wq = (cfp)d_in[4];  cfp bq = (cfp)d_in[5];
  cfp wk = (cfp)d_in[6];  cfp bk = (cfp)d_in[7];
  cfp wv = (cfp)d_in[8];  cfp bv = (cfp)d_in[9];
  cfp we = (cfp)d_in[10]; cfp be = (cfp)d_in[11];
  cfp wo = (cfp)d_in[12]; cfp bo = (cfp)d_in[13];
  cfp ln1g = (cfp)d_in[14]; cfp ln1b = (cfp)d_in[15];
  cfp ln2g = (cfp)d_in[16]; cfp ln2b = (cfp)d_in[17];
  cfp w1 = (cfp)d_in[18]; cfp bf1 = (cfp)d_in[19];
  cfp w2 = (cfp)d_in[20]; cfp bf2 = (cfp)d_in[21];
  float* out = (float*)d_out;
  float* W = (float*)d_ws;   // NH*S*S floats = 32 KB

  hipMemsetAsync(d_ws, 0, NHEAD * SS * SS * sizeof(float), stream);
  edge_bias_kernel<<<NEDGE / 64, 256, 0, stream>>>(edge_attr, edge_index, we, be, W);
  encoder_kernel<<<NB / GPB, 256, 0, stream>>>(x, batch,
      wq, bq, wk, bk, wv, bv, wo, bo,
      ln1g, ln1b, ln2g, ln2b, w1, bf1, w2, bf2, W, out);
}

// Round 3
// 143.178 us; speedup vs baseline: 4.1975x; 1.3222x over previous
//
#include <hip/hip_runtime.h>

#define NB 8192
#define SS 32
#define NEDGE 131072
#define GPB 16                      // graphs per block
#define ITERS (GPB / 2)             // 2 graphs per iteration
#define ATT_SCALE 0.35355339059327373f
#define LN_EPS 1e-5f

typedef const float* __restrict__ cfp;
typedef __attribute__((ext_vector_type(8))) short bfrag;   // 8 bf16
typedef __attribute__((ext_vector_type(4))) float f32x4;

__device__ inline short f2bf(float f) {                    // RNE f32 -> bf16
  union { float f; unsigned u; } un; un.f = f;
  unsigned r = un.u + 0x7FFFu + ((un.u >> 16) & 1u);
  return (short)(r >> 16);
}
__device__ inline unsigned cvt_pk(float lo, float hi) {    // 2xf32 -> bf16x2
  unsigned r;
  asm("v_cvt_pk_bf16_f32 %0, %1, %2" : "=v"(r) : "v"(lo), "v"(hi));
  return r;
}
// swizzled LDS address (shorts): 16B groups XOR'd by row&7
__device__ inline int lad(int row, int col) {
  return row * 64 + (((col >> 3) ^ (row & 7)) * 8) + (col & 7);
}

// ---------------- Kernel 1: sparse edge bias -> compact W[NH][S][S] ----------
__global__ __launch_bounds__(256) void edge_bias_kernel(
    cfp edge_attr, const int* __restrict__ edge_index, cfp we, cfp be,
    float* __restrict__ W) {
  __shared__ float ea[64][68];
  __shared__ float wes[64][8];
  __shared__ float bes[8];
  const int t = threadIdx.x;
  const long ebase = (long)blockIdx.x * 64;
  const float4* src4 = (const float4*)(edge_attr + ebase * 64);
#pragma unroll
  for (int q = 0; q < 4; ++q) {
    int slot = q * 256 + t;
    int eL = slot >> 4, c4 = (slot & 15) * 4;
    float4 v = src4[slot];
    *(float4*)&ea[eL][c4] = v;
  }
  if (t < 128) ((float4*)wes)[t] = ((const float4*)we)[t];
  if (t < 8) bes[t] = be[t];
  __syncthreads();

  const int eL = t >> 2;
  const int h0 = (t & 3) * 2;
  float d0 = 0.f, d1 = 0.f;
#pragma unroll
  for (int k = 0; k < 64; ++k) {
    float a = ea[eL][k];
    d0 += a * wes[k][h0];
    d1 += a * wes[k][h0 + 1];
  }
  const long eG = ebase + eL;
  const int s = edge_index[eG];
  const int d = edge_index[NEDGE + eG];
  atomicAdd(&W[(h0 * SS + s) * SS + d], d0 + bes[h0]);
  atomicAdd(&W[((h0 + 1) * SS + s) * SS + d], d1 + bes[h0 + 1]);
}

// ---------------- Kernel 2: fused encoder, 512 thr, 2 graphs/iter, MFMA attn -
__global__ __launch_bounds__(512, 4) void encoder_kernel(
    cfp x, const int* __restrict__ batch,
    cfp wq, cfp bq, cfp wk, cfp bk, cfp wv, cfp bv, cfp wo, cfp bo,
    cfp ln1g, cfp ln1b, cfp ln2g, cfp ln2b,
    cfp w1, cfp bf1, cfp w2, cfp bf2,
    cfp W, float* __restrict__ out) {

  __shared__ short wt[6][64 * 64];      // wt[m][lad(n,k)] = bf16(w[k][n])
  __shared__ short P[64 * 64], Q[64 * 64], R[64 * 64];
  __shared__ float bias_s[10][64];      // bq bk bv bo b1 b2 ln1g ln1b ln2g ln2b
  __shared__ int batch_s[SS];

  const int t = threadIdx.x;

  // ---- one-time staging ----
  {
    const int n = t & 63, kb = (t >> 6) * 8;
    auto stage = [&](cfp src, short* dst) {
      bfrag p;
#pragma unroll
      for (int j = 0; j < 8; ++j) p[j] = f2bf(src[(kb + j) * 64 + n]);
      *(bfrag*)&dst[lad(n, kb)] = p;
    };
    stage(wq, wt[0]); stage(wk, wt[1]); stage(wv, wt[2]);
    stage(wo, wt[3]); stage(w1, wt[4]); stage(w2, wt[5]);
  }
  if (t < 64) {
    bias_s[0][t] = bq[t];   bias_s[1][t] = bk[t];   bias_s[2][t] = bv[t];
    bias_s[3][t] = bo[t];   bias_s[4][t] = bf1[t];  bias_s[5][t] = bf2[t];
    bias_s[6][t] = ln1g[t]; bias_s[7][t] = ln1b[t];
    bias_s[8][t] = ln2g[t]; bias_s[9][t] = ln2b[t];
  }
  if (t < SS) batch_s[t] = batch[t];
  __syncthreads();

  const int lane = t & 63, w = t >> 6;
  const int g = lane >> 4, r = lane & 15;     // MFMA fragment coords
  const int tr = w >> 1, tc0 = (w & 1) * 2;   // GEMM: M-tile, N-tile pair
  const int s8 = t >> 3, c8 = (t & 7) * 8;    // LN mapping (64 rows x 8 thr)
  const int gW = w >> 2, hb = (w & 3) * 2;    // attn: wave graph + head pair
  const f32x4 zero4 = {0.f, 0.f, 0.f, 0.f};

  auto mm2 = [&](const short* A, const short* Wm, f32x4 acc[2]) {
    const int rr = tr * 16 + r;
    bfrag a0 = *(const bfrag*)&A[lad(rr, g * 8)];
    bfrag a1 = *(const bfrag*)&A[lad(rr, 32 + g * 8)];
#pragma unroll
    for (int i = 0; i < 2; ++i) {
      const int n = (tc0 + i) * 16 + r;
      bfrag b0 = *(const bfrag*)&Wm[lad(n, g * 8)];
      bfrag b1 = *(const bfrag*)&Wm[lad(n, 32 + g * 8)];
      acc[i] = __builtin_amdgcn_mfma_f32_16x16x32_bf16(a0, b0, acc[i], 0, 0, 0);
      acc[i] = __builtin_amdgcn_mfma_f32_16x16x32_bf16(a1, b1, acc[i], 0, 0, 0);
    }
  };

  for (int it = 0; it < ITERS; ++it) {
    const int giter = blockIdx.x * GPB + it * 2;   // first of 2 graphs

    // ---- ph1: LN1(x) -> P (bf16) ----
    {
      float xv[8];
      const float4* px = (const float4*)(x + ((long)(giter * 32 + s8)) * 64 + c8);
      float4 a = px[0], c = px[1];
      xv[0]=a.x; xv[1]=a.y; xv[2]=a.z; xv[3]=a.w;
      xv[4]=c.x; xv[5]=c.y; xv[6]=c.z; xv[7]=c.w;
      float sum = 0.f;
#pragma unroll
      for (int i = 0; i < 8; ++i) sum += xv[i];
      sum += __shfl_xor(sum, 1); sum += __shfl_xor(sum, 2); sum += __shfl_xor(sum, 4);
      const float m = sum * (1.f / 64.f);
      float sq = 0.f;
#pragma unroll
      for (int i = 0; i < 8; ++i) { float dd = xv[i] - m; sq += dd * dd; }
      sq += __shfl_xor(sq, 1); sq += __shfl_xor(sq, 2); sq += __shfl_xor(sq, 4);
      const float rs = rsqrtf(sq * (1.f / 64.f) + LN_EPS);
      bfrag yv;
#pragma unroll
      for (int i = 0; i < 8; ++i)
        yv[i] = f2bf((xv[i] - m) * rs * bias_s[6][c8 + i] + bias_s[7][c8 + i]);
      *(bfrag*)&P[lad(s8, c8)] = yv;
    }
    __syncthreads();                                       // bar A

    // ---- ph2: QKV projections; q*SCALE -> Q, k -> R, v -> P as V^T ----
    {
      const int rr = tr * 16 + r;
      bfrag a0 = *(const bfrag*)&P[lad(rr, g * 8)];
      bfrag a1 = *(const bfrag*)&P[lad(rr, 32 + g * 8)];
      f32x4 acc[3][2];
#pragma unroll
      for (int m = 0; m < 3; ++m) { acc[m][0] = zero4; acc[m][1] = zero4; }
#pragma unroll
      for (int i = 0; i < 2; ++i) {
        const int n = (tc0 + i) * 16 + r;
#pragma unroll
        for (int m = 0; m < 3; ++m) {
          bfrag b0 = *(const bfrag*)&wt[m][lad(n, g * 8)];
          bfrag b1 = *(const bfrag*)&wt[m][lad(n, 32 + g * 8)];
          acc[m][i] = __builtin_amdgcn_mfma_f32_16x16x32_bf16(a0, b0, acc[m][i], 0, 0, 0);
          acc[m][i] = __builtin_amdgcn_mfma_f32_16x16x32_bf16(a1, b1, acc[m][i], 0, 0, 0);
        }
      }
#pragma unroll
      for (int i = 0; i < 2; ++i) {
        const int col = (tc0 + i) * 16 + r;
        const float bq_ = bias_s[0][col], bk_ = bias_s[1][col];
#pragma unroll
        for (int j = 0; j < 4; ++j) {
          const int row = tr * 16 + g * 4 + j;
          const int ad = lad(row, col);
          Q[ad] = f2bf((acc[0][i][j] + bq_) * ATT_SCALE);
          R[ad] = f2bf(acc[1][i][j] + bk_);
        }
      }
      __syncthreads();                                     // bar B (P reads done)
#pragma unroll
      for (int i = 0; i < 2; ++i) {
        const int hd = (tc0 + i) * 16 + r;
        const float bv_ = bias_s[2][hd];
        const int graph = tr >> 1;
        const int tgrp = (tr & 1) * 2 + (g >> 1);
        unsigned p0 = cvt_pk(acc[2][i][0] + bv_, acc[2][i][1] + bv_);
        unsigned p1 = cvt_pk(acc[2][i][2] + bv_, acc[2][i][3] + bv_);
        const int ad = graph * 2048 + hd * 32 + ((tgrp ^ (hd & 3)) * 8) + (g & 1) * 4;
        *(unsigned*)&P[ad] = p0;
        *(unsigned*)&P[ad + 2] = p1;
      }
    }
    __syncthreads();                                       // bar C

    // ---- ph3: attention on MFMA (S^T = K Q^T; softmax lane-local; PV) ----
    {
      const int gidx2 = giter + gW;
#pragma unroll
      for (int u = 0; u < 2; ++u) {
        const int h = hb + u;
        bfrag kf0 = {0,0,0,0,0,0,0,0}, kf1 = kf0;
        if (g == 0) {
          kf0 = *(const bfrag*)&R[lad(gW * 32 + r, h * 8)];
          kf1 = *(const bfrag*)&R[lad(gW * 32 + 16 + r, h * 8)];
        }
#pragma unroll
        for (int st = 0; st < 2; ++st) {
          const int sL = st * 16 + r;
          bfrag qf = {0,0,0,0,0,0,0,0};
          if (g == 0) qf = *(const bfrag*)&Q[lad(gW * 32 + sL, h * 8)];
          f32x4 sc0 = zero4, sc1 = zero4;
          sc0 = __builtin_amdgcn_mfma_f32_16x16x32_bf16(kf0, qf, sc0, 0, 0, 0);
          sc1 = __builtin_amdgcn_mfma_f32_16x16x32_bf16(kf1, qf, sc1, 0, 0, 0);
          f32x4 wb0 = zero4, wb1 = zero4;
          if (batch_s[sL] == gidx2) {
            wb0 = *(const f32x4*)&W[(h * 32 + sL) * 32 + 4 * g];
            wb1 = *(const f32x4*)&W[(h * 32 + sL) * 32 + 16 + 4 * g];
          }
          float v0[4], v1[4];
#pragma unroll
          for (int j = 0; j < 4; ++j) { v0[j] = sc0[j] + wb0[j]; v1[j] = sc1[j] + wb1[j]; }
          float mx = fmaxf(fmaxf(fmaxf(v0[0], v0[1]), fmaxf(v0[2], v0[3])),
                           fmaxf(fmaxf(v1[0], v1[1]), fmaxf(v1[2], v1[3])));
          mx = fmaxf(mx, __shfl_xor(mx, 16));
          mx = fmaxf(mx, __shfl_xor(mx, 32));
          float e0[4], e1[4], ssum = 0.f;
#pragma unroll
          for (int j = 0; j < 4; ++j) {
            e0[j] = __expf(v0[j] - mx); e1[j] = __expf(v1[j] - mx);
            ssum += e0[j] + e1[j];
          }
          ssum += __shfl_xor(ssum, 16);
          ssum += __shfl_xor(ssum, 32);
          const float inv = __builtin_amdgcn_rcpf(ssum);
          // pack P^T to bf16 pairs, permute C-layout -> PV B-frag layout
          unsigned u0 = cvt_pk(e0[0], e0[1]), u1 = cvt_pk(e0[2], e0[3]);
          unsigned u2 = cvt_pk(e1[0], e1[1]), u3 = cvt_pk(e1[2], e1[3]);
          const int srcA = ((g & 1) * 2) * 16 + r, srcB = srcA + 16;
          unsigned A0 = (unsigned)__shfl((int)u0, srcA);
          unsigned A2 = (unsigned)__shfl((int)u2, srcA);
          unsigned B0 = (unsigned)__shfl((int)u1, srcA);
          unsigned B2 = (unsigned)__shfl((int)u3, srcA);
          unsigned C0 = (unsigned)__shfl((int)u0, srcB);
          unsigned C2 = (unsigned)__shfl((int)u2, srcB);
          unsigned D0 = (unsigned)__shfl((int)u1, srcB);
          unsigned D2 = (unsigned)__shfl((int)u3, srcB);
          const bool hi = (g >> 1);
          uint4 bw;
          bw.x = hi ? A2 : A0;
          bw.y = hi ? B2 : B0;
          bw.z = hi ? C2 : C0;
          bw.w = hi ? D2 : D0;
          bfrag pb = *(bfrag*)&bw;
          bfrag vf = {0,0,0,0,0,0,0,0};
          if (r < 8) {
            const int hd = h * 8 + r;
            vf = *(const bfrag*)&P[gW * 2048 + hd * 32 + ((g ^ (hd & 3)) * 8)];
          }
          f32x4 o = zero4;
          o = __builtin_amdgcn_mfma_f32_16x16x32_bf16(vf, pb, o, 0, 0, 0);
          if (g < 2) {
            unsigned w0 = cvt_pk(o[0] * inv, o[1] * inv);
            unsigned w1 = cvt_pk(o[2] * inv, o[3] * inv);
            const int row = gW * 32 + sL;
            const int ad = lad(row, h * 8) + g * 4;
            *(unsigned*)&Q[ad] = w0;
            *(unsigned*)&Q[ad + 2] = w1;
          }
        }
      }
    }
    __syncthreads();                                       // bar D

    // ---- ph4: out-proj + residual; x1 -> R (bf16) + rx regs (f32) ----
    f32x4 rx[2];
    {
      f32x4 acc[2] = {zero4, zero4};
      mm2(Q, wt[3], acc);
#pragma unroll
      for (int i = 0; i < 2; ++i) {
        const int col = (tc0 + i) * 16 + r;
        const float bb = bias_s[3][col];
#pragma unroll
        for (int j = 0; j < 4; ++j) {
          const int row = tr * 16 + g * 4 + j;
          const float xv = x[((long)(giter * 32 + row)) * 64 + col];
          const float v = acc[i][j] + bb + xv;
          rx[i][j] = v;
          R[lad(row, col)] = f2bf(v);
        }
      }
    }
    __syncthreads();                                       // bar E

    // ---- ph5: LN2(x1) -> P ----
    {
      bfrag xv8 = *(const bfrag*)&R[lad(s8, c8)];
      float zv[8];
#pragma unroll
      for (int i = 0; i < 8; ++i) {
        union { unsigned u; float f; } un;
        un.u = ((unsigned)(unsigned short)xv8[i]) << 16;
        zv[i] = un.f;
      }
      float sum = 0.f;
#pragma unroll
      for (int i = 0; i < 8; ++i) sum += zv[i];
      sum += __shfl_xor(sum, 1); sum += __shfl_xor(sum, 2); sum += __shfl_xor(sum, 4);
      const float m = sum * (1.f / 64.f);
      float sq = 0.f;
#pragma unroll
      for (int i = 0; i < 8; ++i) { float dd = zv[i] - m; sq += dd * dd; }
      sq += __shfl_xor(sq, 1); sq += __shfl_xor(sq, 2); sq += __shfl_xor(sq, 4);
      const float rs = rsqrtf(sq * (1.f / 64.f) + LN_EPS);
      bfrag zb;
#pragma unroll
      for (int i = 0; i < 8; ++i)
        zb[i] = f2bf((zv[i] - m) * rs * bias_s[8][c8 + i] + bias_s[9][c8 + i]);
      *(bfrag*)&P[lad(s8, c8)] = zb;
    }
    __syncthreads();                                       // bar F

    // ---- ph6: FFN1 + exact GELU -> Q ----
    {
      f32x4 acc[2] = {zero4, zero4};
      mm2(P, wt[4], acc);
#pragma unroll
      for (int i = 0; i < 2; ++i) {
        const int col = (tc0 + i) * 16 + r;
        const float bb = bias_s[4][col];
#pragma unroll
        for (int j = 0; j < 4; ++j) {
          const int row = tr * 16 + g * 4 + j;
          const float u_ = acc[i][j] + bb;
          Q[lad(row, col)] = f2bf(0.5f * u_ * (1.f + erff(u_ * 0.70710678118654752f)));
        }
      }
    }
    __syncthreads();                                       // bar G

    // ---- ph7: FFN2 + residual -> out ----
    {
      f32x4 acc[2] = {zero4, zero4};
      mm2(Q, wt[5], acc);
#pragma unroll
      for (int i = 0; i < 2; ++i) {
        const int col = (tc0 + i) * 16 + r;
        const float bb = bias_s[5][col];
#pragma unroll
        for (int j = 0; j < 4; ++j) {
          const int row = tr * 16 + g * 4 + j;
          out[((long)(giter * 32 + row)) * 64 + col] = acc[i][j] + bb + rx[i][j];
        }
      }
    }
  }
}

extern "C" void kernel_launch(void* const* d_in, const int* in_sizes, int n_in,
                              void* d_out, int out_size, void* d_ws, size_t ws_size,
                              hipStream_t stream) {
  (void)in_sizes; (void)n_in; (void)out_size; (void)ws_size;
  cfp x         = (cfp)d_in[0];
  cfp edge_attr = (cfp)d_in[1];
  const int* edge_index = (const int*)d_in[2];
  const int* batch      = (const int*)d_in[3];
  cfp wq = (cfp)d_in[4];  cfp bq = (cfp)d_in[5];
  cfp wk = (cfp)d_in[6];  cfp bk = (cfp)d_in[7];
  cfp wv = (cfp)d_in[8];  cfp bv = (cfp)d_in[9];
  cfp we = (cfp)d_in[10]; cfp be = (cfp)d_in[11];
  cfp wo = (cfp)d_in[12]; cfp bo = (cfp)d_in[13];
  cfp ln1g = (cfp)d_in[14]; cfp ln1b = (cfp)d_in[15];
  cfp ln2g = (cfp)d_in[16]; cfp ln2b = (cfp)d_in[17];
  cfp w1 = (cfp)d_in[18]; cfp bf1 = (cfp)d_in[19];
  cfp w2 = (cfp)d_in[20]; cfp bf2 = (cfp)d_in[21];
  float* out = (float*)d_out;
  float* W = (float*)d_ws;   // NH*S*S floats = 32 KB

  hipMemsetAsync(d_ws, 0, 8 * SS * SS * sizeof(float), stream);
  edge_bias_kernel<<<NEDGE / 64, 256, 0, stream>>>(edge_attr, edge_index, we, be, W);
  encoder_kernel<<<NB / GPB, 512, 0, stream>>>(x, batch,
      wq, bq, wk, bk, wv, bv, wo, bo,
      ln1g, ln1b, ln2g, ln2b, w1, bf1, w2, bf2, W, out);
}